// Round 2
// baseline (4448.256 us; speedup 1.0000x reference)
//
#include <hip/hip_runtime.h>
#include <hip/hip_bf16.h>

// SNN forward, MI355X (gfx950). Round 2: t-fused conv2 with v2 in registers.
//  - TAU1 == 1.0  =>  layer-1 stateless: s1 = (a1 >= TH1)  (binary, bf16-exact)
//  - s1 bitpacked in ws (42 MB, L3-resident); unpacked to LDS bf16 per tile.
//  - conv2 fused over all 20 timesteps: v2 state + spike counts in VGPRs.
//  - W2 pre-swizzled in ws so LDS tiles are XOR-swizzled with linear writes.

#define NB    64
#define NCIN  12
#define NC1   128
#define NC2   256
#define NT    20
#define NL    2048
#define GAINF 3.0f
#define THF   0.02f

typedef __bf16 bf16x8 __attribute__((ext_vector_type(8)));
typedef float  f32x4  __attribute__((ext_vector_type(4)));

__device__ __forceinline__ unsigned short f2bf(float f) {
  __hip_bfloat16 h = __float2bfloat16(f);
  return __builtin_bit_cast(unsigned short, h);
}

// ---------------- setup:
//  w1t: [c1][kd(128 zero-padded)] bf16 (swizzle applied at LDS write in conv1)
//  w2t: [tap][c2][c1 ^ ((c2&7)<<3)] bf16  -- PRE-SWIZZLED for linear LDS staging
//  s1p guard rows (l=-4..-1, 2048..2051 per (b,t)) zeroed
__global__ void snn_wsetup_kernel(const float* __restrict__ W1, const float* __restrict__ W2,
                                  unsigned short* __restrict__ w1t, unsigned short* __restrict__ w2t,
                                  unsigned char* __restrict__ s1p) {
  int idx = blockIdx.x * 256 + threadIdx.x;
  if (idx < 9 * 256 * 128) {
    int c1 = idx & 127;
    int c2 = (idx >> 7) & 255;
    int k  = idx >> 15;
    int c1s = c1 ^ ((c2 & 7) << 3);
    w2t[((size_t)k * 256 + c2) * 128 + c1s] = f2bf(W2[((size_t)c2 * 128 + c1) * 9 + k]);
  }
  if (idx < 128 * 128) {
    int c1 = idx >> 7, kd = idx & 127;
    float v = 0.f;
    if (kd < 108) {
      int cin = kd / 9, kk = kd - cin * 9;
      v = W1[((size_t)c1 * 12 + cin) * 9 + kk];
    }
    w1t[idx] = f2bf(v);
  }
  if (idx < NB * NT * 8) {
    int bt = idx >> 3, r8 = idx & 7;
    size_t row = (size_t)bt * 2056 + (r8 < 4 ? r8 : 2048 + r8);  // 0..3, 2052..2055
    *(uint4*)(s1p + row * 16) = make_uint4(0u, 0u, 0u, 0u);
  }
}

// ---------------- conv1 + threshold, fused over t: writes bitpacked s1.
// block = (b, l-tile of 128, t). s1p row layout: [b*20+t][2056 rows][16 B], row l at index l+4.
__global__ __launch_bounds__(256, 2) void snn_conv1_kernel(
    const float* __restrict__ x, const float* __restrict__ b1,
    const unsigned short* __restrict__ w1t, unsigned char* __restrict__ s1p) {
  __shared__ alignas(16) unsigned short ldsB[128 * 128];  // im2col [n][kd] swizzled
  __shared__ alignas(16) unsigned short ldsA[128 * 128];  // W1T [c1][kd] swizzled
  __shared__ float b1s[128];

  const int tid  = threadIdx.x;
  const int lane = tid & 63;
  const int wv   = tid >> 6;
  const int wm   = wv >> 1, wn = wv & 1;
  const int hi   = lane >> 4, lo = lane & 15;
  const int bid  = blockIdx.x;
  const int t    = bid % 20;
  const int r    = bid / 20;
  const int l0   = (r & 15) << 7;
  const int b    = r >> 4;

  {
    const uint4* gA = (const uint4*)w1t;
#pragma unroll
    for (int i = 0; i < 8; ++i) {
      int idx = tid + i * 256;
      unsigned off = (unsigned)idx * 16u;
      unsigned row = off >> 8;
      *(uint4*)((char*)ldsA + (off ^ ((row & 7u) << 4))) = gA[idx];
    }
  }
  if (tid < 128) b1s[tid] = b1[tid];

  for (int i = tid; i < 128 * 20; i += 256) {
    int n = i / 20, c = 108 + (i - n * 20);
    *(unsigned short*)((char*)ldsB + ((unsigned)(n * 256) + (((unsigned)c * 2u) ^ (((unsigned)n & 7u) << 4)))) = 0;
  }
  for (int e = tid; e < NCIN * 136; e += 256) {
    int cin = e / 136, i = e - cin * 136;
    int l = l0 - 4 + i;
    float xv = 0.f;
    if (l >= 0 && l < NL) xv = x[(((size_t)b * NCIN + cin) * NL + l) * NT + t];
    unsigned short hv = f2bf(xv);
    int kd0 = cin * 9;
#pragma unroll
    for (int k = 0; k < 9; ++k) {
      int n = i - k;
      if (n >= 0 && n < 128) {
        *(unsigned short*)((char*)ldsB + ((unsigned)(n * 256) + (((unsigned)(kd0 + k) * 2u) ^ (((unsigned)n & 7u) << 4)))) = hv;
      }
    }
  }
  __syncthreads();

  f32x4 acc[4][4];
#pragma unroll
  for (int mf = 0; mf < 4; ++mf)
#pragma unroll
    for (int nf = 0; nf < 4; ++nf) acc[mf][nf] = (f32x4){0.f, 0.f, 0.f, 0.f};

#pragma unroll
  for (int chunk = 0; chunk < 4; ++chunk) {
    const unsigned kd2 = (unsigned)(chunk * 32 + hi * 8) * 2u;
    bf16x8 af[4], bfr[4];
#pragma unroll
    for (int mf = 0; mf < 4; ++mf) {
      int rr = wm * 64 + mf * 16 + lo;
      af[mf] = *(const bf16x8*)((const char*)ldsA + ((unsigned)(rr * 256) + (kd2 ^ (((unsigned)rr & 7u) << 4))));
    }
#pragma unroll
    for (int nf = 0; nf < 4; ++nf) {
      int rr = wn * 64 + nf * 16 + lo;
      bfr[nf] = *(const bf16x8*)((const char*)ldsB + ((unsigned)(rr * 256) + (kd2 ^ (((unsigned)rr & 7u) << 4))));
    }
#pragma unroll
    for (int mf = 0; mf < 4; ++mf)
#pragma unroll
      for (int nf = 0; nf < 4; ++nf)
        acc[mf][nf] = __builtin_amdgcn_mfma_f32_16x16x32_bf16(af[mf], bfr[nf], acc[mf][nf], 0, 0, 0);
  }
  __syncthreads();

  // pack spikes: bit p of byte [l][jb] = spike(c1 = jb*8+p)
  unsigned char* ldsP = (unsigned char*)ldsB;
#pragma unroll
  for (int mf = 0; mf < 4; ++mf) {
    int c1b = wm * 64 + mf * 16 + hi * 4;
#pragma unroll
    for (int nf = 0; nf < 4; ++nf) {
      int lrow = wn * 64 + nf * 16 + lo;
      unsigned n4 = 0;
      n4 |= (GAINF * (acc[mf][nf][0] + b1s[c1b + 0]) >= THF) ? 1u : 0u;
      n4 |= (GAINF * (acc[mf][nf][1] + b1s[c1b + 1]) >= THF) ? 2u : 0u;
      n4 |= (GAINF * (acc[mf][nf][2] + b1s[c1b + 2]) >= THF) ? 4u : 0u;
      n4 |= (GAINF * (acc[mf][nf][3] + b1s[c1b + 3]) >= THF) ? 8u : 0u;
      unsigned p = (unsigned)__shfl_xor((int)n4, 16);  // partner hi^1
      if ((hi & 1) == 0) {
        ldsP[lrow * 16 + (wm * 8 + mf * 2 + (hi >> 1))] = (unsigned char)(n4 | (p << 4));
      }
    }
  }
  __syncthreads();

  if (tid < 128) {
    uint4 v = *(const uint4*)(ldsP + tid * 16);
    *(uint4*)(s1p + ((size_t)(b * 20 + t) * 2056 + 4 + l0 + tid) * 16) = v;
  }
}

// ---------------- conv2 + LIF2 fused over all t; v2 state and counts in registers.
// block = (b, c2-half, l-tile of 128); 2 blocks/CU.
__global__ __launch_bounds__(256, 2) void snn_conv2_kernel(
    const unsigned char* __restrict__ s1p, const unsigned short* __restrict__ w2t,
    const float* __restrict__ b2, float* __restrict__ counts) {
  __shared__ alignas(16) unsigned short ldsS[136 * 128];  // s1 bf16, swizzle key ((n+4)&7)
  __shared__ alignas(16) unsigned short ldsW[128 * 128];  // W2 tap (content pre-swizzled)

  const int tid  = threadIdx.x;
  const int lane = tid & 63;
  const int wv   = tid >> 6;
  const int wm   = wv >> 1, wn = wv & 1;
  const int hi   = lane >> 4, lo = lane & 15;
  const int b    = blockIdx.x >> 5;
  const int r5   = blockIdx.x & 31;
  const int c2b  = r5 >> 4;
  const int l0   = (r5 & 15) << 7;

  float b2r[4][4];
#pragma unroll
  for (int mf = 0; mf < 4; ++mf)
#pragma unroll
    for (int j = 0; j < 4; ++j)
      b2r[mf][j] = b2[c2b * 128 + wm * 64 + mf * 16 + hi * 4 + j];

  f32x4 v2s[4][4];
  int cnt[4][4];
#pragma unroll
  for (int mf = 0; mf < 4; ++mf)
#pragma unroll
    for (int k = 0; k < 4; ++k) { v2s[mf][k] = (f32x4){0.f, 0.f, 0.f, 0.f}; cnt[mf][k] = 0; }

  // W2 tap prefetch registers (T14 async-split staging)
  uint4 gv[8];
  {
    const char* gW = (const char*)(w2t);  // tap 0
#pragma unroll
    for (int i = 0; i < 8; ++i)
      gv[i] = *(const uint4*)(gW + ((size_t)c2b * 128 * 128 + 0) * 2 + (size_t)(tid + i * 256) * 16);
  }

  const float it2 = 1.0f / 0.9f;

  for (int t = 0; t < 20; ++t) {
    __syncthreads();  // previous t's ldsS reads complete
    // unpack s1 bits -> ldsS bf16 (272 half-rows over 256 threads)
    const unsigned char* sp = s1p + ((size_t)(b * 20 + t) * 2056 + l0) * 16;
#pragma unroll
    for (int it = 0; it < 2; ++it) {
      int hr = tid + it * 256;
      if (hr < 272) {
        int n = hr >> 1, h = hr & 1;
        uint2 bits = *(const uint2*)(sp + n * 16 + h * 8);
        unsigned swz = (unsigned)((n + 4) & 7) << 4;
        char* rowp = (char*)ldsS + n * 256;
#pragma unroll
        for (int g = 0; g < 16; ++g) {
          unsigned y4 = (g < 8) ? ((bits.x >> (g * 4)) & 15u) : ((bits.y >> ((g - 8) * 4)) & 15u);
          unsigned w0 = (y4 & 1u) * 0x3F80u + (y4 & 2u) * 0x1FC00000u;
          unsigned w1 = ((y4 >> 2) & 1u) * 0x3F80u + ((y4 >> 2) & 2u) * 0x1FC00000u;
          uint2 wr; wr.x = w0; wr.y = w1;
          *(uint2*)(rowp + (((unsigned)(h * 128 + g * 8)) ^ swz)) = wr;
        }
      }
    }

    f32x4 acc[4][4];
#pragma unroll
    for (int mf = 0; mf < 4; ++mf)
#pragma unroll
      for (int nf = 0; nf < 4; ++nf) acc[mf][nf] = (f32x4){0.f, 0.f, 0.f, 0.f};

    for (int tap = 0; tap < 9; ++tap) {
      __syncthreads();  // ldsW free (prev tap reads done); tap0: publishes ldsS
      // write prefetched W2 tap into LDS (linear; content pre-swizzled)
#pragma unroll
      for (int i = 0; i < 8; ++i)
        *(uint4*)((char*)ldsW + (size_t)(tid + i * 256) * 16) = gv[i];
      // issue prefetch of next tap (wraps to tap 0 for next t)
      {
        int tapn = (tap == 8) ? 0 : (tap + 1);
        const char* gW = (const char*)(w2t + ((size_t)tapn * 256 + c2b * 128) * 128);
#pragma unroll
        for (int i = 0; i < 8; ++i)
          gv[i] = *(const uint4*)(gW + (size_t)(tid + i * 256) * 16);
      }
      __syncthreads();  // ldsW (and tap0: ldsS) visible

#pragma unroll
      for (int chunk = 0; chunk < 4; ++chunk) {
        const unsigned kd2 = (unsigned)(chunk * 32 + hi * 8) * 2u;
        bf16x8 af[4], bfr[4];
#pragma unroll
        for (int mf = 0; mf < 4; ++mf) {
          int rr = wm * 64 + mf * 16 + lo;
          af[mf] = *(const bf16x8*)((const char*)ldsW + ((unsigned)(rr * 256) + (kd2 ^ (((unsigned)rr & 7u) << 4))));
        }
#pragma unroll
        for (int nf = 0; nf < 4; ++nf) {
          int rr = wn * 64 + nf * 16 + lo + tap;  // s1 row l0-4+rr
          bfr[nf] = *(const bf16x8*)((const char*)ldsS + ((unsigned)(rr * 256) + (kd2 ^ (((unsigned)(rr + 4) & 7u) << 4))));
        }
#pragma unroll
        for (int mf = 0; mf < 4; ++mf)
#pragma unroll
          for (int nf = 0; nf < 4; ++nf)
            acc[mf][nf] = __builtin_amdgcn_mfma_f32_16x16x32_bf16(af[mf], bfr[nf], acc[mf][nf], 0, 0, 0);
      }
    }

    // LIF2 epilogue: pure register ops
#pragma unroll
    for (int mf = 0; mf < 4; ++mf) {
#pragma unroll
      for (int nf = 0; nf < 4; ++nf) {
#pragma unroll
        for (int j = 0; j < 4; ++j) {
          float a2 = GAINF * (acc[mf][nf][j] + b2r[mf][j]);
          float vo = v2s[mf][nf][j];
          float vn = vo + (a2 - vo) * it2;
          int sp2 = (vn >= THF) ? 1 : 0;
          v2s[mf][nf][j] = sp2 ? 0.f : vn;
          cnt[mf][j] += sp2;
        }
      }
    }
  }

  // reduce counts: sum over lo lanes (l within fragment), one atomic per (hi,mf,j)
#pragma unroll
  for (int mf = 0; mf < 4; ++mf)
#pragma unroll
    for (int j = 0; j < 4; ++j) {
      int c = cnt[mf][j];
      c += __shfl_xor(c, 1);
      c += __shfl_xor(c, 2);
      c += __shfl_xor(c, 4);
      c += __shfl_xor(c, 8);
      if (lo == 0) {
        int c2g = c2b * 128 + wm * 64 + mf * 16 + hi * 4 + j;
        atomicAdd(&counts[b * NC2 + c2g], (float)c);
      }
    }
}

// ---------------- final FC
__global__ void snn_fc_kernel(const float* __restrict__ counts, const float* __restrict__ Wfc,
                              const float* __restrict__ bfc, float* __restrict__ out) {
  int tid = threadIdx.x;  // 256 = 64 b x 4 cls
  int b = tid >> 2, cls = tid & 3;
  float s = 0.f;
  for (int c = 0; c < 256; ++c) s += counts[b * 256 + c] * Wfc[cls * 256 + c];
  out[tid] = s * (1.0f / ((float)NT * (float)NL)) + bfc[cls];
}

extern "C" void kernel_launch(void* const* d_in, const int* in_sizes, int n_in,
                              void* d_out, int out_size, void* d_ws, size_t ws_size,
                              hipStream_t stream) {
  const float* x   = (const float*)d_in[0];
  const float* W1  = (const float*)d_in[1];
  const float* b1  = (const float*)d_in[2];
  const float* W2  = (const float*)d_in[3];
  const float* b2  = (const float*)d_in[4];
  const float* Wfc = (const float*)d_in[5];
  const float* bfc = (const float*)d_in[6];
  float* out = (float*)d_out;
  char* ws = (char*)d_ws;

  const size_t SZ_S1P = (size_t)NB * NT * 2056 * 16;   // 42,106,880 (bitpacked s1 + guards)
  const size_t SZ_W2T = (size_t)9 * 256 * 128 * 2;     // 589,824
  const size_t SZ_W1T = (size_t)128 * 128 * 2;         // 32,768
  const size_t SZ_CNT = (size_t)NB * NC2 * 4;          // 65,536

  const size_t OFF_S1P = 0;
  const size_t OFF_W2T = OFF_S1P + SZ_S1P;
  const size_t OFF_W1T = OFF_W2T + SZ_W2T;
  const size_t OFF_CNT = OFF_W1T + SZ_W1T;
  const size_t NEEDED  = OFF_CNT + SZ_CNT;
  if (ws_size < NEEDED) return;

  unsigned char*  s1p = (unsigned char*)(ws + OFF_S1P);
  unsigned short* w2t = (unsigned short*)(ws + OFF_W2T);
  unsigned short* w1t = (unsigned short*)(ws + OFF_W1T);
  float* counts = (float*)(ws + OFF_CNT);

  hipMemsetAsync(counts, 0, SZ_CNT, stream);
  snn_wsetup_kernel<<<1152, 256, 0, stream>>>(W1, W2, w1t, w2t, s1p);
  snn_conv1_kernel<<<NB * 16 * NT, 256, 0, stream>>>(x, b1, w1t, s1p);
  snn_conv2_kernel<<<NB * 2 * 16, 256, 0, stream>>>(s1p, w2t, b2, counts);
  snn_fc_kernel<<<1, 256, 0, stream>>>(counts, Wfc, bfc, out);
}

// Round 3
// 1959.507 us; speedup vs baseline: 2.2701x; 2.2701x over previous
//
#include <hip/hip_runtime.h>
#include <hip/hip_bf16.h>

// SNN forward, MI355X (gfx950). Round 3: t-fused conv2, spill-free (64c2 x 128l tile),
// global_load_lds double-buffered W2 staging, conflict-free bit-unpack.
//  - TAU1 == 1.0  =>  layer-1 stateless: s1 = (a1 >= TH1)  (binary, bf16-exact)
//  - s1 bitpacked in ws (42 MB); unpacked to LDS bf16 per tile per t.
//  - conv2 fused over all 20 timesteps: v2 state + spike counts in VGPRs.
//  - W2 pre-swizzled in ws so LDS tiles are XOR-swizzled with LINEAR writes (glds-compatible).

#define NB    64
#define NCIN  12
#define NC1   128
#define NC2   256
#define NT    20
#define NL    2048
#define GAINF 3.0f
#define THF   0.02f

typedef __bf16 bf16x8 __attribute__((ext_vector_type(8)));
typedef float  f32x4  __attribute__((ext_vector_type(4)));

__device__ __forceinline__ unsigned short f2bf(float f) {
  __hip_bfloat16 h = __float2bfloat16(f);
  return __builtin_bit_cast(unsigned short, h);
}

// ---------------- setup:
//  w1t: [c1][kd(128 zero-padded)] bf16 (swizzle applied at LDS write in conv1)
//  w2t: [tap][c2][c1 ^ ((c2&7)<<3)] bf16  -- PRE-SWIZZLED for linear LDS staging
//  s1p guard rows (l=-4..-1, 2048..2051 per (b,t)) zeroed
__global__ void snn_wsetup_kernel(const float* __restrict__ W1, const float* __restrict__ W2,
                                  unsigned short* __restrict__ w1t, unsigned short* __restrict__ w2t,
                                  unsigned char* __restrict__ s1p) {
  int idx = blockIdx.x * 256 + threadIdx.x;
  if (idx < 9 * 256 * 128) {
    int c1 = idx & 127;
    int c2 = (idx >> 7) & 255;
    int k  = idx >> 15;
    int c1s = c1 ^ ((c2 & 7) << 3);
    w2t[((size_t)k * 256 + c2) * 128 + c1s] = f2bf(W2[((size_t)c2 * 128 + c1) * 9 + k]);
  }
  if (idx < 128 * 128) {
    int c1 = idx >> 7, kd = idx & 127;
    float v = 0.f;
    if (kd < 108) {
      int cin = kd / 9, kk = kd - cin * 9;
      v = W1[((size_t)c1 * 12 + cin) * 9 + kk];
    }
    w1t[idx] = f2bf(v);
  }
  if (idx < NB * NT * 8) {
    int bt = idx >> 3, r8 = idx & 7;
    size_t row = (size_t)bt * 2056 + (r8 < 4 ? r8 : 2048 + r8);  // 0..3, 2052..2055
    *(uint4*)(s1p + row * 16) = make_uint4(0u, 0u, 0u, 0u);
  }
}

// ---------------- conv1 + threshold, fused over t: writes bitpacked s1.
// block = (b, l-tile of 128, t). s1p row layout: [b*20+t][2056 rows][16 B], row l at index l+4.
__global__ __launch_bounds__(256, 2) void snn_conv1_kernel(
    const float* __restrict__ x, const float* __restrict__ b1,
    const unsigned short* __restrict__ w1t, unsigned char* __restrict__ s1p) {
  __shared__ alignas(16) unsigned short ldsB[128 * 128];  // im2col [n][kd] swizzled
  __shared__ alignas(16) unsigned short ldsA[128 * 128];  // W1T [c1][kd] swizzled
  __shared__ float b1s[128];

  const int tid  = threadIdx.x;
  const int lane = tid & 63;
  const int wv   = tid >> 6;
  const int wm   = wv >> 1, wn = wv & 1;
  const int hi   = lane >> 4, lo = lane & 15;
  const int bid  = blockIdx.x;
  const int t    = bid % 20;
  const int r    = bid / 20;
  const int l0   = (r & 15) << 7;
  const int b    = r >> 4;

  {
    const uint4* gA = (const uint4*)w1t;
#pragma unroll
    for (int i = 0; i < 8; ++i) {
      int idx = tid + i * 256;
      unsigned off = (unsigned)idx * 16u;
      unsigned row = off >> 8;
      *(uint4*)((char*)ldsA + (off ^ ((row & 7u) << 4))) = gA[idx];
    }
  }
  if (tid < 128) b1s[tid] = b1[tid];

  for (int i = tid; i < 128 * 20; i += 256) {
    int n = i / 20, c = 108 + (i - n * 20);
    *(unsigned short*)((char*)ldsB + ((unsigned)(n * 256) + (((unsigned)c * 2u) ^ (((unsigned)n & 7u) << 4)))) = 0;
  }
  for (int e = tid; e < NCIN * 136; e += 256) {
    int cin = e / 136, i = e - cin * 136;
    int l = l0 - 4 + i;
    float xv = 0.f;
    if (l >= 0 && l < NL) xv = x[(((size_t)b * NCIN + cin) * NL + l) * NT + t];
    unsigned short hv = f2bf(xv);
    int kd0 = cin * 9;
#pragma unroll
    for (int k = 0; k < 9; ++k) {
      int n = i - k;
      if (n >= 0 && n < 128) {
        *(unsigned short*)((char*)ldsB + ((unsigned)(n * 256) + (((unsigned)(kd0 + k) * 2u) ^ (((unsigned)n & 7u) << 4)))) = hv;
      }
    }
  }
  __syncthreads();

  f32x4 acc[4][4];
#pragma unroll
  for (int mf = 0; mf < 4; ++mf)
#pragma unroll
    for (int nf = 0; nf < 4; ++nf) acc[mf][nf] = (f32x4){0.f, 0.f, 0.f, 0.f};

#pragma unroll
  for (int chunk = 0; chunk < 4; ++chunk) {
    const unsigned kd2 = (unsigned)(chunk * 32 + hi * 8) * 2u;
    bf16x8 af[4], bfr[4];
#pragma unroll
    for (int mf = 0; mf < 4; ++mf) {
      int rr = wm * 64 + mf * 16 + lo;
      af[mf] = *(const bf16x8*)((const char*)ldsA + ((unsigned)(rr * 256) + (kd2 ^ (((unsigned)rr & 7u) << 4))));
    }
#pragma unroll
    for (int nf = 0; nf < 4; ++nf) {
      int rr = wn * 64 + nf * 16 + lo;
      bfr[nf] = *(const bf16x8*)((const char*)ldsB + ((unsigned)(rr * 256) + (kd2 ^ (((unsigned)rr & 7u) << 4))));
    }
#pragma unroll
    for (int mf = 0; mf < 4; ++mf)
#pragma unroll
      for (int nf = 0; nf < 4; ++nf)
        acc[mf][nf] = __builtin_amdgcn_mfma_f32_16x16x32_bf16(af[mf], bfr[nf], acc[mf][nf], 0, 0, 0);
  }
  __syncthreads();

  // pack spikes: bit p of byte [l][jb] = spike(c1 = jb*8+p)
  unsigned char* ldsP = (unsigned char*)ldsB;
#pragma unroll
  for (int mf = 0; mf < 4; ++mf) {
    int c1b = wm * 64 + mf * 16 + hi * 4;
#pragma unroll
    for (int nf = 0; nf < 4; ++nf) {
      int lrow = wn * 64 + nf * 16 + lo;
      unsigned n4 = 0;
      n4 |= (GAINF * (acc[mf][nf][0] + b1s[c1b + 0]) >= THF) ? 1u : 0u;
      n4 |= (GAINF * (acc[mf][nf][1] + b1s[c1b + 1]) >= THF) ? 2u : 0u;
      n4 |= (GAINF * (acc[mf][nf][2] + b1s[c1b + 2]) >= THF) ? 4u : 0u;
      n4 |= (GAINF * (acc[mf][nf][3] + b1s[c1b + 3]) >= THF) ? 8u : 0u;
      unsigned p = (unsigned)__shfl_xor((int)n4, 16);  // partner hi^1
      if ((hi & 1) == 0) {
        ldsP[lrow * 16 + (wm * 8 + mf * 2 + (hi >> 1))] = (unsigned char)(n4 | (p << 4));
      }
    }
  }
  __syncthreads();

  if (tid < 128) {
    uint4 v = *(const uint4*)(ldsP + tid * 16);
    *(uint4*)(s1p + ((size_t)(b * 20 + t) * 2056 + 4 + l0 + tid) * 16) = v;
  }
}

// stage one 16 KB W2 tap tile (pre-swizzled content) into LDS, linear copy.
__device__ __forceinline__ void stage_w2(const unsigned short* __restrict__ w2t,
                                         char* ldsWbase, int tap, int c2q, int wv, int lane) {
  const char* gsrc = (const char*)(w2t + ((size_t)tap * 256 + (size_t)c2q * 64) * 128);
#pragma unroll
  for (int i = 0; i < 4; ++i) {
    int ubase = wv * 4096 + i * 1024;  // wave-uniform LDS offset
#if __has_builtin(__builtin_amdgcn_global_load_lds)
    __builtin_amdgcn_global_load_lds(
        (const __attribute__((address_space(1))) void*)(gsrc + ubase + lane * 16),
        (__attribute__((address_space(3))) void*)(ldsWbase + ubase), 16, 0, 0);
#else
    *(uint4*)(ldsWbase + ubase + lane * 16) = *(const uint4*)(gsrc + ubase + lane * 16);
#endif
  }
}

// ---------------- conv2 + LIF2 fused over all t; v2 state and counts in registers.
// block = (b, c2-quarter of 64, l-tile of 128); wave = 32 c2 x 64 l; 2 blocks/CU.
__global__ __launch_bounds__(256, 2) void snn_conv2_kernel(
    const unsigned char* __restrict__ s1p, const unsigned short* __restrict__ w2t,
    const float* __restrict__ b2, float* __restrict__ counts) {
  __shared__ alignas(16) unsigned short ldsS[136 * 128];     // s1 bf16, swizzle key ((n+4)&7)
  __shared__ alignas(16) unsigned short ldsW[2 * 64 * 128];  // W2 tap double-buffer

  const int tid  = threadIdx.x;
  const int lane = tid & 63;
  const int wv   = tid >> 6;
  const int wm   = wv >> 1, wn = wv & 1;
  const int hi   = lane >> 4, lo = lane & 15;
  const int b    = blockIdx.x >> 6;
  const int r6   = blockIdx.x & 63;
  const int c2q  = r6 >> 4;
  const int l0   = (r6 & 15) << 7;

  float b2r[2][4];
#pragma unroll
  for (int mf = 0; mf < 2; ++mf)
#pragma unroll
    for (int j = 0; j < 4; ++j)
      b2r[mf][j] = b2[c2q * 64 + wm * 32 + mf * 16 + hi * 4 + j];

  f32x4 v2s[2][4];
  int cnt[2][4];
#pragma unroll
  for (int mf = 0; mf < 2; ++mf)
#pragma unroll
    for (int k = 0; k < 4; ++k) { v2s[mf][k] = (f32x4){0.f, 0.f, 0.f, 0.f}; cnt[mf][k] = 0; }

  // prologue: stage tap 0 into buf 0
  stage_w2(w2t, (char*)ldsW, 0, c2q, wv, lane);
  int cur = 0;

  const float it2 = 1.0f / 0.9f;

  for (int t = 0; t < 20; ++t) {
    // unpack s1 bits -> ldsS bf16. Prev t's ldsS readers finished at the last tap barrier.
    // thread unit u = (row n, quarter q): reads 4 packed bytes, writes 64 B contiguous (^swz).
    const unsigned char* sp = s1p + ((size_t)(b * 20 + t) * 2056 + l0) * 16;
#pragma unroll
    for (int it = 0; it < 3; ++it) {
      int u = it * 256 + tid;
      if (u < 544) {
        int n = u >> 2, q = u & 3;
        unsigned bits = *(const unsigned*)(sp + (size_t)u * 4);
        unsigned swz = (unsigned)((n + 4) & 7) << 4;
        char* rowp = (char*)ldsS + n * 256;
#pragma unroll
        for (int i = 0; i < 4; ++i) {
          unsigned by = (bits >> (i * 8)) & 255u;
          uint4 w;
          w.x = (by & 1u)        * 0x3F80u + ((by >> 1) & 1u) * 0x3F800000u;
          w.y = ((by >> 2) & 1u) * 0x3F80u + ((by >> 3) & 1u) * 0x3F800000u;
          w.z = ((by >> 4) & 1u) * 0x3F80u + ((by >> 5) & 1u) * 0x3F800000u;
          w.w = ((by >> 6) & 1u) * 0x3F80u + ((by >> 7) & 1u) * 0x3F800000u;
          *(uint4*)(rowp + ((unsigned)(q * 64 + i * 16) ^ swz)) = w;
        }
      }
    }
    __syncthreads();  // publish ldsS; also drains prologue/wrapped W2 stage (vmcnt(0) before barrier)

    f32x4 acc[2][4];
#pragma unroll
    for (int mf = 0; mf < 2; ++mf)
#pragma unroll
      for (int nf = 0; nf < 4; ++nf) acc[mf][nf] = (f32x4){0.f, 0.f, 0.f, 0.f};

    for (int tap = 0; tap < 9; ++tap) {
      // prefetch next tap into the other buffer (wraps to tap 0 for next t; dummy at very end)
      stage_w2(w2t, (char*)ldsW + ((cur ^ 1) << 14), (tap == 8) ? 0 : tap + 1, c2q, wv, lane);

      const char* ldsWc = (const char*)ldsW + (cur << 14);
#pragma unroll
      for (int chunk = 0; chunk < 4; ++chunk) {
        const unsigned kd2 = (unsigned)(chunk * 32 + hi * 8) * 2u;
        bf16x8 af[2], bfr[4];
#pragma unroll
        for (int mf = 0; mf < 2; ++mf) {
          int rr = wm * 32 + mf * 16 + lo;
          af[mf] = *(const bf16x8*)(ldsWc + ((unsigned)(rr * 256) + (kd2 ^ (((unsigned)rr & 7u) << 4))));
        }
#pragma unroll
        for (int nf = 0; nf < 4; ++nf) {
          int rs = wn * 64 + nf * 16 + lo + tap;  // s1 row l0-4+rs
          bfr[nf] = *(const bf16x8*)((const char*)ldsS + ((unsigned)(rs * 256) + (kd2 ^ (((unsigned)(rs + 4) & 7u) << 4))));
        }
#pragma unroll
        for (int mf = 0; mf < 2; ++mf)
#pragma unroll
          for (int nf = 0; nf < 4; ++nf)
            acc[mf][nf] = __builtin_amdgcn_mfma_f32_16x16x32_bf16(af[mf], bfr[nf], acc[mf][nf], 0, 0, 0);
      }
      __syncthreads();  // drains this tap's prefetch (vmcnt(0)) + rendezvous; next tap reads safely
      cur ^= 1;
    }

    // LIF2 epilogue: pure register ops
#pragma unroll
    for (int mf = 0; mf < 2; ++mf) {
#pragma unroll
      for (int nf = 0; nf < 4; ++nf) {
#pragma unroll
        for (int j = 0; j < 4; ++j) {
          float a2 = GAINF * (acc[mf][nf][j] + b2r[mf][j]);
          float vo = v2s[mf][nf][j];
          float vn = vo + (a2 - vo) * it2;
          int sp2 = (vn >= THF) ? 1 : 0;
          v2s[mf][nf][j] = sp2 ? 0.f : vn;
          cnt[mf][j] += sp2;
        }
      }
    }
  }

  // reduce counts over lo lanes (l within fragment), one atomic per (hi,mf,j)
#pragma unroll
  for (int mf = 0; mf < 2; ++mf)
#pragma unroll
    for (int j = 0; j < 4; ++j) {
      int c = cnt[mf][j];
      c += __shfl_xor(c, 1);
      c += __shfl_xor(c, 2);
      c += __shfl_xor(c, 4);
      c += __shfl_xor(c, 8);
      if (lo == 0) {
        int c2g = c2q * 64 + wm * 32 + mf * 16 + hi * 4 + j;
        atomicAdd(&counts[b * NC2 + c2g], (float)c);
      }
    }
}

// ---------------- final FC
__global__ void snn_fc_kernel(const float* __restrict__ counts, const float* __restrict__ Wfc,
                              const float* __restrict__ bfc, float* __restrict__ out) {
  int tid = threadIdx.x;  // 256 = 64 b x 4 cls
  int b = tid >> 2, cls = tid & 3;
  float s = 0.f;
  for (int c = 0; c < 256; ++c) s += counts[b * 256 + c] * Wfc[cls * 256 + c];
  out[tid] = s * (1.0f / ((float)NT * (float)NL)) + bfc[cls];
}

extern "C" void kernel_launch(void* const* d_in, const int* in_sizes, int n_in,
                              void* d_out, int out_size, void* d_ws, size_t ws_size,
                              hipStream_t stream) {
  const float* x   = (const float*)d_in[0];
  const float* W1  = (const float*)d_in[1];
  const float* b1  = (const float*)d_in[2];
  const float* W2  = (const float*)d_in[3];
  const float* b2  = (const float*)d_in[4];
  const float* Wfc = (const float*)d_in[5];
  const float* bfc = (const float*)d_in[6];
  float* out = (float*)d_out;
  char* ws = (char*)d_ws;

  const size_t SZ_S1P = (size_t)NB * NT * 2056 * 16;   // 42,106,880 (bitpacked s1 + guards)
  const size_t SZ_W2T = (size_t)9 * 256 * 128 * 2;     // 589,824
  const size_t SZ_W1T = (size_t)128 * 128 * 2;         // 32,768
  const size_t SZ_CNT = (size_t)NB * NC2 * 4;          // 65,536

  const size_t OFF_S1P = 0;
  const size_t OFF_W2T = OFF_S1P + SZ_S1P;
  const size_t OFF_W1T = OFF_W2T + SZ_W2T;
  const size_t OFF_CNT = OFF_W1T + SZ_W1T;
  const size_t NEEDED  = OFF_CNT + SZ_CNT;
  if (ws_size < NEEDED) return;

  unsigned char*  s1p = (unsigned char*)(ws + OFF_S1P);
  unsigned short* w2t = (unsigned short*)(ws + OFF_W2T);
  unsigned short* w1t = (unsigned short*)(ws + OFF_W1T);
  float* counts = (float*)(ws + OFF_CNT);

  hipMemsetAsync(counts, 0, SZ_CNT, stream);
  snn_wsetup_kernel<<<1152, 256, 0, stream>>>(W1, W2, w1t, w2t, s1p);
  snn_conv1_kernel<<<NB * 16 * NT, 256, 0, stream>>>(x, b1, w1t, s1p);
  snn_conv2_kernel<<<NB * 4 * 16, 256, 0, stream>>>(s1p, w2t, b2, counts);
  snn_fc_kernel<<<1, 256, 0, stream>>>(counts, Wfc, bfc, out);
}

// Round 4
// 1741.097 us; speedup vs baseline: 2.5549x; 1.1254x over previous
//
#include <hip/hip_runtime.h>
#include <hip/hip_bf16.h>

// SNN forward, MI355X (gfx950). Round 4: conv2 with 64x64 wave tiles (1.5x fewer
// LDS reads per FLOP), 512-thread blocks (128 c2 x 256 l), double-buffered W2
// staging via global_load_lds, s1p register prefetch, setprio around MFMA.
//  - TAU1 == 1.0  =>  layer-1 stateless: s1 = (a1 >= TH1)  (binary, bf16-exact)
//  - s1 bitpacked in ws (42 MB, L3-resident); unpacked to LDS bf16 per tile per t.
//  - conv2 fused over all 20 timesteps: v2 state + spike counts in VGPRs.
//  - W2 pre-swizzled in ws so LDS tiles are XOR-swizzled with LINEAR writes.

#define NB    64
#define NCIN  12
#define NC1   128
#define NC2   256
#define NT    20
#define NL    2048
#define GAINF 3.0f
#define THF   0.02f

typedef __bf16 bf16x8 __attribute__((ext_vector_type(8)));
typedef float  f32x4  __attribute__((ext_vector_type(4)));

__device__ __forceinline__ unsigned short f2bf(float f) {
  __hip_bfloat16 h = __float2bfloat16(f);
  return __builtin_bit_cast(unsigned short, h);
}

// ---------------- setup:
//  w1t: [c1][kd(128 zero-padded)] bf16 (swizzle applied at LDS write in conv1)
//  w2t: [tap][c2][c1 ^ ((c2&7)<<3)] bf16  -- PRE-SWIZZLED for linear LDS staging
//  s1p guard rows (l=-4..-1, 2048..2051 per (b,t)) zeroed
__global__ void snn_wsetup_kernel(const float* __restrict__ W1, const float* __restrict__ W2,
                                  unsigned short* __restrict__ w1t, unsigned short* __restrict__ w2t,
                                  unsigned char* __restrict__ s1p) {
  int idx = blockIdx.x * 256 + threadIdx.x;
  if (idx < 9 * 256 * 128) {
    int c1 = idx & 127;
    int c2 = (idx >> 7) & 255;
    int k  = idx >> 15;
    int c1s = c1 ^ ((c2 & 7) << 3);
    w2t[((size_t)k * 256 + c2) * 128 + c1s] = f2bf(W2[((size_t)c2 * 128 + c1) * 9 + k]);
  }
  if (idx < 128 * 128) {
    int c1 = idx >> 7, kd = idx & 127;
    float v = 0.f;
    if (kd < 108) {
      int cin = kd / 9, kk = kd - cin * 9;
      v = W1[((size_t)c1 * 12 + cin) * 9 + kk];
    }
    w1t[idx] = f2bf(v);
  }
  if (idx < NB * NT * 8) {
    int bt = idx >> 3, r8 = idx & 7;
    size_t row = (size_t)bt * 2056 + (r8 < 4 ? r8 : 2048 + r8);  // 0..3, 2052..2055
    *(uint4*)(s1p + row * 16) = make_uint4(0u, 0u, 0u, 0u);
  }
}

// ---------------- conv1 + threshold, fused over t: writes bitpacked s1.
// block = (b, l-tile of 128, t). s1p row layout: [b*20+t][2056 rows][16 B], row l at index l+4.
__global__ __launch_bounds__(256, 2) void snn_conv1_kernel(
    const float* __restrict__ x, const float* __restrict__ b1,
    const unsigned short* __restrict__ w1t, unsigned char* __restrict__ s1p) {
  __shared__ alignas(16) unsigned short ldsB[128 * 128];  // im2col [n][kd] swizzled
  __shared__ alignas(16) unsigned short ldsA[128 * 128];  // W1T [c1][kd] swizzled
  __shared__ float b1s[128];

  const int tid  = threadIdx.x;
  const int lane = tid & 63;
  const int wv   = tid >> 6;
  const int wm   = wv >> 1, wn = wv & 1;
  const int hi   = lane >> 4, lo = lane & 15;
  const int bid  = blockIdx.x;
  const int t    = bid % 20;
  const int r    = bid / 20;
  const int l0   = (r & 15) << 7;
  const int b    = r >> 4;

  {
    const uint4* gA = (const uint4*)w1t;
#pragma unroll
    for (int i = 0; i < 8; ++i) {
      int idx = tid + i * 256;
      unsigned off = (unsigned)idx * 16u;
      unsigned row = off >> 8;
      *(uint4*)((char*)ldsA + (off ^ ((row & 7u) << 4))) = gA[idx];
    }
  }
  if (tid < 128) b1s[tid] = b1[tid];

  for (int i = tid; i < 128 * 20; i += 256) {
    int n = i / 20, c = 108 + (i - n * 20);
    *(unsigned short*)((char*)ldsB + ((unsigned)(n * 256) + (((unsigned)c * 2u) ^ (((unsigned)n & 7u) << 4)))) = 0;
  }
  for (int e = tid; e < NCIN * 136; e += 256) {
    int cin = e / 136, i = e - cin * 136;
    int l = l0 - 4 + i;
    float xv = 0.f;
    if (l >= 0 && l < NL) xv = x[(((size_t)b * NCIN + cin) * NL + l) * NT + t];
    unsigned short hv = f2bf(xv);
    int kd0 = cin * 9;
#pragma unroll
    for (int k = 0; k < 9; ++k) {
      int n = i - k;
      if (n >= 0 && n < 128) {
        *(unsigned short*)((char*)ldsB + ((unsigned)(n * 256) + (((unsigned)(kd0 + k) * 2u) ^ (((unsigned)n & 7u) << 4)))) = hv;
      }
    }
  }
  __syncthreads();

  f32x4 acc[4][4];
#pragma unroll
  for (int mf = 0; mf < 4; ++mf)
#pragma unroll
    for (int nf = 0; nf < 4; ++nf) acc[mf][nf] = (f32x4){0.f, 0.f, 0.f, 0.f};

#pragma unroll
  for (int chunk = 0; chunk < 4; ++chunk) {
    const unsigned kd2 = (unsigned)(chunk * 32 + hi * 8) * 2u;
    bf16x8 af[4], bfr[4];
#pragma unroll
    for (int mf = 0; mf < 4; ++mf) {
      int rr = wm * 64 + mf * 16 + lo;
      af[mf] = *(const bf16x8*)((const char*)ldsA + ((unsigned)(rr * 256) + (kd2 ^ (((unsigned)rr & 7u) << 4))));
    }
#pragma unroll
    for (int nf = 0; nf < 4; ++nf) {
      int rr = wn * 64 + nf * 16 + lo;
      bfr[nf] = *(const bf16x8*)((const char*)ldsB + ((unsigned)(rr * 256) + (kd2 ^ (((unsigned)rr & 7u) << 4))));
    }
#pragma unroll
    for (int mf = 0; mf < 4; ++mf)
#pragma unroll
      for (int nf = 0; nf < 4; ++nf)
        acc[mf][nf] = __builtin_amdgcn_mfma_f32_16x16x32_bf16(af[mf], bfr[nf], acc[mf][nf], 0, 0, 0);
  }
  __syncthreads();

  // pack spikes: bit p of byte [l][jb] = spike(c1 = jb*8+p)
  unsigned char* ldsP = (unsigned char*)ldsB;
#pragma unroll
  for (int mf = 0; mf < 4; ++mf) {
    int c1b = wm * 64 + mf * 16 + hi * 4;
#pragma unroll
    for (int nf = 0; nf < 4; ++nf) {
      int lrow = wn * 64 + nf * 16 + lo;
      unsigned n4 = 0;
      n4 |= (GAINF * (acc[mf][nf][0] + b1s[c1b + 0]) >= THF) ? 1u : 0u;
      n4 |= (GAINF * (acc[mf][nf][1] + b1s[c1b + 1]) >= THF) ? 2u : 0u;
      n4 |= (GAINF * (acc[mf][nf][2] + b1s[c1b + 2]) >= THF) ? 4u : 0u;
      n4 |= (GAINF * (acc[mf][nf][3] + b1s[c1b + 3]) >= THF) ? 8u : 0u;
      unsigned p = (unsigned)__shfl_xor((int)n4, 16);  // partner hi^1
      if ((hi & 1) == 0) {
        ldsP[lrow * 16 + (wm * 8 + mf * 2 + (hi >> 1))] = (unsigned char)(n4 | (p << 4));
      }
    }
  }
  __syncthreads();

  if (tid < 128) {
    uint4 v = *(const uint4*)(ldsP + tid * 16);
    *(uint4*)(s1p + ((size_t)(b * 20 + t) * 2056 + 4 + l0 + tid) * 16) = v;
  }
}

// stage one 32 KB W2 tap tile (pre-swizzled content) into an LDS buffer, linear copy.
// 512 threads: wave wv covers [wv*4096, (wv+1)*4096).
__device__ __forceinline__ void stage_w2(const unsigned short* __restrict__ w2t,
                                         char* ldsWbuf, int tap, int c2h, int wv, int lane) {
  const char* gsrc = (const char*)w2t + (size_t)tap * 65536 + (size_t)c2h * 32768;
#pragma unroll
  for (int i = 0; i < 4; ++i) {
    int ubase = wv * 4096 + i * 1024;  // wave-uniform LDS offset
    __builtin_amdgcn_global_load_lds(
        (const __attribute__((address_space(1))) void*)(gsrc + ubase + lane * 16),
        (__attribute__((address_space(3))) void*)(ldsWbuf + ubase), 16, 0, 0);
  }
}

// ---------------- conv2 + LIF2 fused over all t; v2 state and counts in registers.
// block = (b, c2-half of 128, l-tile of 256); 8 waves, wave tile 64 c2 x 64 l; 1 block/CU.
__global__ __attribute__((amdgpu_flat_work_group_size(512, 512), amdgpu_waves_per_eu(2, 2)))
void snn_conv2_kernel(const unsigned char* __restrict__ s1p, const unsigned short* __restrict__ w2t,
                      const float* __restrict__ b2, float* __restrict__ counts) {
  __shared__ alignas(16) unsigned short ldsS[264 * 128];      // s1 bf16, swizzle key ((n+4)&7)
  __shared__ alignas(16) unsigned short ldsW[2 * 128 * 128];  // W2 tap double-buffer (32 KB each)

  const int tid  = threadIdx.x;
  const int lane = tid & 63;
  const int wv   = tid >> 6;   // 0..7
  const int wm   = wv >> 2;    // 0..1 : c2 64-block
  const int wn   = wv & 3;     // 0..3 : l  64-block
  const int hi   = lane >> 4, lo = lane & 15;
  const int bid  = blockIdx.x;
  const int b    = bid >> 4;
  const int r4   = bid & 15;
  const int c2h  = r4 >> 3;
  const int l0   = (r4 & 7) << 8;

  float b2r[4][4];
#pragma unroll
  for (int mf = 0; mf < 4; ++mf)
#pragma unroll
    for (int j = 0; j < 4; ++j)
      b2r[mf][j] = b2[c2h * 128 + wm * 64 + mf * 16 + hi * 4 + j];

  f32x4 v2s[4][4];
  int cnt[4][4];
#pragma unroll
  for (int mf = 0; mf < 4; ++mf)
#pragma unroll
    for (int k = 0; k < 4; ++k) { v2s[mf][k] = (f32x4){0.f, 0.f, 0.f, 0.f}; cnt[mf][k] = 0; }

  // s1p bit prefetch for t=0 (1056 units of 4 B; thread covers tid, tid+512, [tid<32] tid+1024)
  const unsigned char* spbase = s1p + ((size_t)(b * 20) * 2056 + l0) * 16;
  unsigned pf0 = *(const unsigned*)(spbase + (size_t)tid * 4);
  unsigned pf1 = *(const unsigned*)(spbase + (size_t)(tid + 512) * 4);
  unsigned pf2 = (tid < 32) ? *(const unsigned*)(spbase + (size_t)(tid + 1024) * 4) : 0u;

  // prologue: stage tap 0 into buf 0
  stage_w2(w2t, (char*)ldsW, 0, c2h, wv, lane);
  int cur = 0;

  const float it2 = 1.0f / 0.9f;

  for (int t = 0; t < 20; ++t) {
    // unpack s1 bits -> ldsS bf16. Prev t's tap-8 barrier guarantees ldsS is free.
#pragma unroll
    for (int rep = 0; rep < 3; ++rep) {
      int u = rep * 512 + tid;
      unsigned bits = (rep == 0) ? pf0 : (rep == 1) ? pf1 : pf2;
      if (rep < 2 || tid < 32) {
        int n = u >> 2, q = u & 3;
        unsigned swz = (unsigned)((n + 4) & 7) << 4;
        char* rowp = (char*)ldsS + n * 256;
#pragma unroll
        for (int i = 0; i < 4; ++i) {
          unsigned by = (bits >> (i * 8)) & 255u;
          uint4 w;
          w.x = (by & 1u)        * 0x3F80u + ((by >> 1) & 1u) * 0x3F800000u;
          w.y = ((by >> 2) & 1u) * 0x3F80u + ((by >> 3) & 1u) * 0x3F800000u;
          w.z = ((by >> 4) & 1u) * 0x3F80u + ((by >> 5) & 1u) * 0x3F800000u;
          w.w = ((by >> 6) & 1u) * 0x3F80u + ((by >> 7) & 1u) * 0x3F800000u;
          *(uint4*)(rowp + ((unsigned)(q * 64 + i * 16) ^ swz)) = w;
        }
      }
    }
    __syncthreads();  // publish ldsS (tap-0 W2 stage was drained at a previous barrier)

    f32x4 acc[4][4];
#pragma unroll
    for (int mf = 0; mf < 4; ++mf)
#pragma unroll
      for (int nf = 0; nf < 4; ++nf) acc[mf][nf] = (f32x4){0.f, 0.f, 0.f, 0.f};

    for (int tap = 0; tap < 9; ++tap) {
      // prefetch next tap into the other buffer (wraps to tap 0 for next t);
      // in flight across this tap's MFMA cluster, drained at the barrier below.
      stage_w2(w2t, (char*)ldsW + ((cur ^ 1) << 15), (tap == 8) ? 0 : tap + 1, c2h, wv, lane);

      const char* ldsWc = (const char*)ldsW + (cur << 15);
      __builtin_amdgcn_s_setprio(1);
#pragma unroll
      for (int chunk = 0; chunk < 4; ++chunk) {
        const unsigned kd2 = (unsigned)(chunk * 32 + hi * 8) * 2u;
        bf16x8 af[4], bfr[4];
#pragma unroll
        for (int mf = 0; mf < 4; ++mf) {
          int rr = wm * 64 + mf * 16 + lo;
          af[mf] = *(const bf16x8*)(ldsWc + ((unsigned)(rr * 256) + (kd2 ^ (((unsigned)rr & 7u) << 4))));
        }
#pragma unroll
        for (int nf = 0; nf < 4; ++nf) {
          int rs = wn * 64 + nf * 16 + lo + tap;  // s1 row l0-4+rs
          bfr[nf] = *(const bf16x8*)((const char*)ldsS + ((unsigned)(rs * 256) + (kd2 ^ (((unsigned)(rs + 4) & 7u) << 4))));
        }
#pragma unroll
        for (int mf = 0; mf < 4; ++mf)
#pragma unroll
          for (int nf = 0; nf < 4; ++nf)
            acc[mf][nf] = __builtin_amdgcn_mfma_f32_16x16x32_bf16(af[mf], bfr[nf], acc[mf][nf], 0, 0, 0);
      }
      __builtin_amdgcn_s_setprio(0);
      __syncthreads();  // drains this tap's prefetch (vmcnt(0)); next tap reads safely
      cur ^= 1;
    }

    // issue s1p prefetch for t+1; flies during the LIF epilogue
    if (t < 19) {
      const unsigned char* spn = s1p + ((size_t)(b * 20 + t + 1) * 2056 + l0) * 16;
      pf0 = *(const unsigned*)(spn + (size_t)tid * 4);
      pf1 = *(const unsigned*)(spn + (size_t)(tid + 512) * 4);
      pf2 = (tid < 32) ? *(const unsigned*)(spn + (size_t)(tid + 1024) * 4) : 0u;
    }

    // LIF2 epilogue: pure register ops
#pragma unroll
    for (int mf = 0; mf < 4; ++mf) {
#pragma unroll
      for (int nf = 0; nf < 4; ++nf) {
#pragma unroll
        for (int j = 0; j < 4; ++j) {
          float a2 = GAINF * (acc[mf][nf][j] + b2r[mf][j]);
          float vo = v2s[mf][nf][j];
          float vn = vo + (a2 - vo) * it2;
          int sp2 = (vn >= THF) ? 1 : 0;
          v2s[mf][nf][j] = sp2 ? 0.f : vn;
          cnt[mf][j] += sp2;
        }
      }
    }
  }

  // reduce counts over lo lanes (l within fragment), one atomic per (hi,mf,j)
#pragma unroll
  for (int mf = 0; mf < 4; ++mf)
#pragma unroll
    for (int j = 0; j < 4; ++j) {
      int c = cnt[mf][j];
      c += __shfl_xor(c, 1);
      c += __shfl_xor(c, 2);
      c += __shfl_xor(c, 4);
      c += __shfl_xor(c, 8);
      if (lo == 0) {
        int c2g = c2h * 128 + wm * 64 + mf * 16 + hi * 4 + j;
        atomicAdd(&counts[b * NC2 + c2g], (float)c);
      }
    }
}

// ---------------- final FC
__global__ void snn_fc_kernel(const float* __restrict__ counts, const float* __restrict__ Wfc,
                              const float* __restrict__ bfc, float* __restrict__ out) {
  int tid = threadIdx.x;  // 256 = 64 b x 4 cls
  int b = tid >> 2, cls = tid & 3;
  float s = 0.f;
  for (int c = 0; c < 256; ++c) s += counts[b * 256 + c] * Wfc[cls * 256 + c];
  out[tid] = s * (1.0f / ((float)NT * (float)NL)) + bfc[cls];
}

extern "C" void kernel_launch(void* const* d_in, const int* in_sizes, int n_in,
                              void* d_out, int out_size, void* d_ws, size_t ws_size,
                              hipStream_t stream) {
  const float* x   = (const float*)d_in[0];
  const float* W1  = (const float*)d_in[1];
  const float* b1  = (const float*)d_in[2];
  const float* W2  = (const float*)d_in[3];
  const float* b2  = (const float*)d_in[4];
  const float* Wfc = (const float*)d_in[5];
  const float* bfc = (const float*)d_in[6];
  float* out = (float*)d_out;
  char* ws = (char*)d_ws;

  const size_t SZ_S1P = (size_t)NB * NT * 2056 * 16;   // 42,106,880 (bitpacked s1 + guards)
  const size_t SZ_W2T = (size_t)9 * 256 * 128 * 2;     // 589,824
  const size_t SZ_W1T = (size_t)128 * 128 * 2;         // 32,768
  const size_t SZ_CNT = (size_t)NB * NC2 * 4;          // 65,536

  const size_t OFF_S1P = 0;
  const size_t OFF_W2T = OFF_S1P + SZ_S1P;
  const size_t OFF_W1T = OFF_W2T + SZ_W2T;
  const size_t OFF_CNT = OFF_W1T + SZ_W1T;
  const size_t NEEDED  = OFF_CNT + SZ_CNT;
  if (ws_size < NEEDED) return;

  unsigned char*  s1p = (unsigned char*)(ws + OFF_S1P);
  unsigned short* w2t = (unsigned short*)(ws + OFF_W2T);
  unsigned short* w1t = (unsigned short*)(ws + OFF_W1T);
  float* counts = (float*)(ws + OFF_CNT);

  hipMemsetAsync(counts, 0, SZ_CNT, stream);
  snn_wsetup_kernel<<<1152, 256, 0, stream>>>(W1, W2, w1t, w2t, s1p);
  snn_conv1_kernel<<<NB * 16 * NT, 256, 0, stream>>>(x, b1, w1t, s1p);
  snn_conv2_kernel<<<NB * 16, 512, 0, stream>>>(s1p, w2t, b2, counts);
  snn_fc_kernel<<<1, 256, 0, stream>>>(counts, Wfc, bfc, out);
}

// Round 5
// 1049.250 us; speedup vs baseline: 4.2395x; 1.6594x over previous
//
#include <hip/hip_runtime.h>
#include <hip/hip_bf16.h>

// SNN forward, MI355X (gfx950). Round 5: conv2 in INT8 (spikes are exactly 0/1;
// W2 quantized with fixed scale S=4310 since |W2| < 1/sqrt(1152)), W2 LDS-resident
// for all 9 taps (144 KB) -> NO per-tap barriers; spike bits kept packed in LDS
// (4.2 KB) and expanded per-fragment with nibble-multiply tricks.
//  - TAU1 == 1.0  =>  layer-1 stateless: s1 = (a1 >= TH1)  (binary)
//  - conv2 fused over all 20 timesteps: v2 state + spike counts in VGPRs.
//  - dot product is exact integer; only error source is W2 quantization (~1e-4 abs).

#define NB    64
#define NCIN  12
#define NC1   128
#define NC2   256
#define NT    20
#define NL    2048
#define GAINF 3.0f
#define THF   0.02f
#define W2SCALE 4310.0f

typedef __bf16 bf16x8 __attribute__((ext_vector_type(8)));
typedef float  f32x4  __attribute__((ext_vector_type(4)));
typedef int    i32x4  __attribute__((ext_vector_type(4)));

__device__ __forceinline__ unsigned short f2bf(float f) {
  __hip_bfloat16 h = __float2bfloat16(f);
  return __builtin_bit_cast(unsigned short, h);
}

// ---------------- setup:
//  w1t: [c1][kd(128 zero-padded)] bf16
//  w2q: [tap][c2h][ (c2l*128 + c1) ^ ((c2l&15)<<4) ] int8, pre-swizzled for linear glds
//  s1p guard rows (l=-4..-1, 2048..2051 per (b,t)) zeroed
__global__ void snn_wsetup_kernel(const float* __restrict__ W1, const float* __restrict__ W2,
                                  unsigned short* __restrict__ w1t, unsigned char* __restrict__ w2q,
                                  unsigned char* __restrict__ s1p) {
  int idx = blockIdx.x * 256 + threadIdx.x;
  if (idx < 9 * 256 * 128) {
    int c1 = idx & 127;
    int c2 = (idx >> 7) & 255;
    int k  = idx >> 15;
    int c2h = c2 >> 7, c2l = c2 & 127;
    int dst = k * 32768 + c2h * 16384 + (((c2l * 128 + c1)) ^ ((c2l & 15) << 4));
    int q = __float2int_rn(W2[((size_t)c2 * 128 + c1) * 9 + k] * W2SCALE);
    w2q[dst] = (unsigned char)(signed char)q;
  }
  if (idx < 128 * 128) {
    int c1 = idx >> 7, kd = idx & 127;
    float v = 0.f;
    if (kd < 108) {
      int cin = kd / 9, kk = kd - cin * 9;
      v = W1[((size_t)c1 * 12 + cin) * 9 + kk];
    }
    w1t[idx] = f2bf(v);
  }
  if (idx < NB * NT * 8) {
    int bt = idx >> 3, r8 = idx & 7;
    size_t row = (size_t)bt * 2056 + (r8 < 4 ? r8 : 2048 + r8);  // 0..3, 2052..2055
    *(uint4*)(s1p + row * 16) = make_uint4(0u, 0u, 0u, 0u);
  }
}

// ---------------- conv1 + threshold, fused over t: writes bitpacked s1.
// block = (b, l-tile of 128, t). s1p row layout: [b*20+t][2056 rows][16 B], row l at index l+4.
__global__ __launch_bounds__(256, 2) void snn_conv1_kernel(
    const float* __restrict__ x, const float* __restrict__ b1,
    const unsigned short* __restrict__ w1t, unsigned char* __restrict__ s1p) {
  __shared__ alignas(16) unsigned short ldsB[128 * 128];  // im2col [n][kd] swizzled
  __shared__ alignas(16) unsigned short ldsA[128 * 128];  // W1T [c1][kd] swizzled
  __shared__ float b1s[128];

  const int tid  = threadIdx.x;
  const int lane = tid & 63;
  const int wv   = tid >> 6;
  const int wm   = wv >> 1, wn = wv & 1;
  const int hi   = lane >> 4, lo = lane & 15;
  const int bid  = blockIdx.x;
  const int t    = bid % 20;
  const int r    = bid / 20;
  const int l0   = (r & 15) << 7;
  const int b    = r >> 4;

  {
    const uint4* gA = (const uint4*)w1t;
#pragma unroll
    for (int i = 0; i < 8; ++i) {
      int idx = tid + i * 256;
      unsigned off = (unsigned)idx * 16u;
      unsigned row = off >> 8;
      *(uint4*)((char*)ldsA + (off ^ ((row & 7u) << 4))) = gA[idx];
    }
  }
  if (tid < 128) b1s[tid] = b1[tid];

  for (int i = tid; i < 128 * 20; i += 256) {
    int n = i / 20, c = 108 + (i - n * 20);
    *(unsigned short*)((char*)ldsB + ((unsigned)(n * 256) + (((unsigned)c * 2u) ^ (((unsigned)n & 7u) << 4)))) = 0;
  }
  for (int e = tid; e < NCIN * 136; e += 256) {
    int cin = e / 136, i = e - cin * 136;
    int l = l0 - 4 + i;
    float xv = 0.f;
    if (l >= 0 && l < NL) xv = x[(((size_t)b * NCIN + cin) * NL + l) * NT + t];
    unsigned short hv = f2bf(xv);
    int kd0 = cin * 9;
#pragma unroll
    for (int k = 0; k < 9; ++k) {
      int n = i - k;
      if (n >= 0 && n < 128) {
        *(unsigned short*)((char*)ldsB + ((unsigned)(n * 256) + (((unsigned)(kd0 + k) * 2u) ^ (((unsigned)n & 7u) << 4)))) = hv;
      }
    }
  }
  __syncthreads();

  f32x4 acc[4][4];
#pragma unroll
  for (int mf = 0; mf < 4; ++mf)
#pragma unroll
    for (int nf = 0; nf < 4; ++nf) acc[mf][nf] = (f32x4){0.f, 0.f, 0.f, 0.f};

#pragma unroll
  for (int chunk = 0; chunk < 4; ++chunk) {
    const unsigned kd2 = (unsigned)(chunk * 32 + hi * 8) * 2u;
    bf16x8 af[4], bfr[4];
#pragma unroll
    for (int mf = 0; mf < 4; ++mf) {
      int rr = wm * 64 + mf * 16 + lo;
      af[mf] = *(const bf16x8*)((const char*)ldsA + ((unsigned)(rr * 256) + (kd2 ^ (((unsigned)rr & 7u) << 4))));
    }
#pragma unroll
    for (int nf = 0; nf < 4; ++nf) {
      int rr = wn * 64 + nf * 16 + lo;
      bfr[nf] = *(const bf16x8*)((const char*)ldsB + ((unsigned)(rr * 256) + (kd2 ^ (((unsigned)rr & 7u) << 4))));
    }
#pragma unroll
    for (int mf = 0; mf < 4; ++mf)
#pragma unroll
      for (int nf = 0; nf < 4; ++nf)
        acc[mf][nf] = __builtin_amdgcn_mfma_f32_16x16x32_bf16(af[mf], bfr[nf], acc[mf][nf], 0, 0, 0);
  }
  __syncthreads();

  // pack spikes: bit p of byte [l][jb] = spike(c1 = jb*8+p)
  unsigned char* ldsP = (unsigned char*)ldsB;
#pragma unroll
  for (int mf = 0; mf < 4; ++mf) {
    int c1b = wm * 64 + mf * 16 + hi * 4;
#pragma unroll
    for (int nf = 0; nf < 4; ++nf) {
      int lrow = wn * 64 + nf * 16 + lo;
      unsigned n4 = 0;
      n4 |= (GAINF * (acc[mf][nf][0] + b1s[c1b + 0]) >= THF) ? 1u : 0u;
      n4 |= (GAINF * (acc[mf][nf][1] + b1s[c1b + 1]) >= THF) ? 2u : 0u;
      n4 |= (GAINF * (acc[mf][nf][2] + b1s[c1b + 2]) >= THF) ? 4u : 0u;
      n4 |= (GAINF * (acc[mf][nf][3] + b1s[c1b + 3]) >= THF) ? 8u : 0u;
      unsigned p = (unsigned)__shfl_xor((int)n4, 16);  // partner hi^1
      if ((hi & 1) == 0) {
        ldsP[lrow * 16 + (wm * 8 + mf * 2 + (hi >> 1))] = (unsigned char)(n4 | (p << 4));
      }
    }
  }
  __syncthreads();

  if (tid < 128) {
    uint4 v = *(const uint4*)(ldsP + tid * 16);
    *(uint4*)(s1p + ((size_t)(b * 20 + t) * 2056 + 4 + l0 + tid) * 16) = v;
  }
}

// ---------------- conv2 (i8) + LIF2 fused over all t; v2 state and counts in registers.
// block = (b, c2-half of 128, l-tile of 256); 8 waves (2 wm x 4 wn), wave tile 64x64.
// W2 resident in LDS for all 9 taps; spike bits packed in LDS; no per-tap barriers.
__global__ __attribute__((amdgpu_flat_work_group_size(512, 512), amdgpu_waves_per_eu(2, 2)))
void snn_conv2_kernel(const unsigned char* __restrict__ s1p, const unsigned char* __restrict__ w2q,
                      const float* __restrict__ b2, float* __restrict__ counts) {
  __shared__ alignas(16) unsigned char ldsW[9 * 16384];   // 144 KB: [tap][(c2l*128+c1)^((c2l&15)<<4)]
  __shared__ alignas(16) unsigned char ldsBits[264 * 16]; // 4224 B: row n = spikes l0-4+n, 128 bits

  const int tid  = threadIdx.x;
  const int lane = tid & 63;
  const int wv   = tid >> 6;   // 0..7
  const int wm   = wv >> 2;    // 0..1 : c2 64-block
  const int wn   = wv & 3;     // 0..3 : l  64-block
  const int hi   = lane >> 4, lo = lane & 15;
  const int bid  = blockIdx.x;
  const int b    = bid >> 4;
  const int r4   = bid & 15;
  const int c2h  = r4 >> 3;
  const int l0   = (r4 & 7) << 8;

  // stage all 9 W2 tap tiles (16 KB each, pre-swizzled) into LDS, linear glds
#pragma unroll
  for (int tt = 0; tt < 9; ++tt) {
#pragma unroll
    for (int i = 0; i < 2; ++i) {
      int ub = wv * 2048 + i * 1024;
      __builtin_amdgcn_global_load_lds(
          (const __attribute__((address_space(1))) void*)(w2q + (size_t)tt * 32768 + (size_t)c2h * 16384 + ub + lane * 16),
          (__attribute__((address_space(3))) void*)(ldsW + tt * 16384 + ub), 16, 0, 0);
    }
  }

  // copy spike bits for t=0
  {
    const unsigned char* sp0 = s1p + ((size_t)(b * 20) * 2056 + l0) * 16;
    if (tid < 264) {
      uint4 v = *(const uint4*)(sp0 + (size_t)tid * 16);
      *(uint4*)(ldsBits + tid * 16) = v;
    }
  }

  float gb2[4][4];
#pragma unroll
  for (int mf = 0; mf < 4; ++mf)
#pragma unroll
    for (int j = 0; j < 4; ++j)
      gb2[mf][j] = GAINF * b2[c2h * 128 + wm * 64 + mf * 16 + hi * 4 + j];

  f32x4 v2s[4][4];
  int cnt[4][4];
#pragma unroll
  for (int mf = 0; mf < 4; ++mf)
#pragma unroll
    for (int k = 0; k < 4; ++k) { v2s[mf][k] = (f32x4){0.f, 0.f, 0.f, 0.f}; cnt[mf][k] = 0; }

  __syncthreads();  // drains glds (vmcnt 0 before barrier) + publishes bits t=0

  const float it2 = 1.0f / 0.9f;
  const float isc = GAINF / W2SCALE;

  for (int t = 0; t < 20; ++t) {
    // issue next-t bit prefetch early; lands before the store at loop bottom
    uint4 nb;
    if (t < 19 && tid < 264) {
      const unsigned char* spn = s1p + ((size_t)(b * 20 + t + 1) * 2056 + l0) * 16;
      nb = *(const uint4*)(spn + (size_t)tid * 16);
    }

    i32x4 acc[4][4];
#pragma unroll
    for (int mf = 0; mf < 4; ++mf)
#pragma unroll
      for (int nf = 0; nf < 4; ++nf) acc[mf][nf] = (i32x4){0, 0, 0, 0};

#pragma unroll 3
    for (int tap = 0; tap < 9; ++tap) {
      const unsigned char* wbase = ldsW + (tap << 14);
#pragma unroll
      for (int chunk = 0; chunk < 2; ++chunk) {
        const int off = chunk * 64 + hi * 16;
        i32x4 af[4], bfr[4];
#pragma unroll
        for (int mf = 0; mf < 4; ++mf) {
          int rr = wm * 64 + mf * 16 + lo;
          af[mf] = *(const i32x4*)(wbase + (((unsigned)(rr * 128 + off)) ^ (((unsigned)rr & 15u) << 4)));
        }
#pragma unroll
        for (int nf = 0; nf < 4; ++nf) {
          int rs = wn * 64 + nf * 16 + lo + tap;  // spike row l0-4+rs
          unsigned v = *(const unsigned short*)(ldsBits + rs * 16 + chunk * 8 + hi * 2);
          i32x4 bx;
          bx.x = (int)(((v & 15u) * 0x204081u) & 0x01010101u);
          bx.y = (int)((((v >> 4) & 15u) * 0x204081u) & 0x01010101u);
          bx.z = (int)((((v >> 8) & 15u) * 0x204081u) & 0x01010101u);
          bx.w = (int)((((v >> 12) & 15u) * 0x204081u) & 0x01010101u);
          bfr[nf] = bx;
        }
#pragma unroll
        for (int mf = 0; mf < 4; ++mf)
#pragma unroll
          for (int nf = 0; nf < 4; ++nf)
            acc[mf][nf] = __builtin_amdgcn_mfma_i32_16x16x64_i8(af[mf], bfr[nf], acc[mf][nf], 0, 0, 0);
      }
    }

    // LIF2 epilogue: pure register ops; a2 = dot*GAIN/S + GAIN*b2
#pragma unroll
    for (int mf = 0; mf < 4; ++mf) {
#pragma unroll
      for (int nf = 0; nf < 4; ++nf) {
#pragma unroll
        for (int j = 0; j < 4; ++j) {
          float a2 = (float)acc[mf][nf][j] * isc + gb2[mf][j];
          float vo = v2s[mf][nf][j];
          float vn = vo + (a2 - vo) * it2;
          int sp2 = (vn >= THF) ? 1 : 0;
          v2s[mf][nf][j] = sp2 ? 0.f : vn;
          cnt[mf][j] += sp2;
        }
      }
    }

    __syncthreads();  // all waves done reading bits t
    if (t < 19 && tid < 264) *(uint4*)(ldsBits + tid * 16) = nb;
    __syncthreads();  // bits t+1 published
  }

  // reduce counts over lo lanes (l within fragment), one atomic per (hi,mf,j)
#pragma unroll
  for (int mf = 0; mf < 4; ++mf)
#pragma unroll
    for (int j = 0; j < 4; ++j) {
      int c = cnt[mf][j];
      c += __shfl_xor(c, 1);
      c += __shfl_xor(c, 2);
      c += __shfl_xor(c, 4);
      c += __shfl_xor(c, 8);
      if (lo == 0) {
        int c2g = c2h * 128 + wm * 64 + mf * 16 + hi * 4 + j;
        atomicAdd(&counts[b * NC2 + c2g], (float)c);
      }
    }
}

// ---------------- final FC
__global__ void snn_fc_kernel(const float* __restrict__ counts, const float* __restrict__ Wfc,
                              const float* __restrict__ bfc, float* __restrict__ out) {
  int tid = threadIdx.x;  // 256 = 64 b x 4 cls
  int b = tid >> 2, cls = tid & 3;
  float s = 0.f;
  for (int c = 0; c < 256; ++c) s += counts[b * 256 + c] * Wfc[cls * 256 + c];
  out[tid] = s * (1.0f / ((float)NT * (float)NL)) + bfc[cls];
}

extern "C" void kernel_launch(void* const* d_in, const int* in_sizes, int n_in,
                              void* d_out, int out_size, void* d_ws, size_t ws_size,
                              hipStream_t stream) {
  const float* x   = (const float*)d_in[0];
  const float* W1  = (const float*)d_in[1];
  const float* b1  = (const float*)d_in[2];
  const float* W2  = (const float*)d_in[3];
  const float* b2  = (const float*)d_in[4];
  const float* Wfc = (const float*)d_in[5];
  const float* bfc = (const float*)d_in[6];
  float* out = (float*)d_out;
  char* ws = (char*)d_ws;

  const size_t SZ_S1P = (size_t)NB * NT * 2056 * 16;   // 42,106,880 (bitpacked s1 + guards)
  const size_t SZ_W2Q = (size_t)9 * 256 * 128;         // 294,912 (int8, pre-swizzled)
  const size_t SZ_W1T = (size_t)128 * 128 * 2;         // 32,768
  const size_t SZ_CNT = (size_t)NB * NC2 * 4;          // 65,536

  const size_t OFF_S1P = 0;
  const size_t OFF_W2Q = OFF_S1P + SZ_S1P;
  const size_t OFF_W1T = OFF_W2Q + SZ_W2Q;
  const size_t OFF_CNT = OFF_W1T + SZ_W1T;
  const size_t NEEDED  = OFF_CNT + SZ_CNT;
  if (ws_size < NEEDED) return;

  unsigned char*  s1p = (unsigned char*)(ws + OFF_S1P);
  unsigned char*  w2q = (unsigned char*)(ws + OFF_W2Q);
  unsigned short* w1t = (unsigned short*)(ws + OFF_W1T);
  float* counts = (float*)(ws + OFF_CNT);

  hipMemsetAsync(counts, 0, SZ_CNT, stream);
  snn_wsetup_kernel<<<1152, 256, 0, stream>>>(W1, W2, w1t, w2q, s1p);
  snn_conv1_kernel<<<NB * 16 * NT, 256, 0, stream>>>(x, b1, w1t, s1p);
  snn_conv2_kernel<<<NB * 16, 512, 0, stream>>>(s1p, w2q, b2, counts);
  snn_fc_kernel<<<1, 256, 0, stream>>>(counts, Wfc, bfc, out);
}